// Round 4
// baseline (128.629 us; speedup 1.0000x reference)
//
#include <hip/hip_runtime.h>
#include <stdint.h>

#define EPS 1e-5f
#define N_NODES 8192

typedef __attribute__((ext_vector_type(8))) short short8;
typedef __attribute__((ext_vector_type(4))) float floatx4;
typedef __attribute__((ext_vector_type(2))) float floatx2;
typedef __attribute__((ext_vector_type(4))) unsigned short ushortx4;

__device__ __forceinline__ unsigned short f2bf(float f) {
    uint32_t u = __float_as_uint(f);
    u += 0x7FFFu + ((u >> 16) & 1u);
    return (unsigned short)(u >> 16);
}

// ---------------- prep ----------------
// blocks    0..1023 : x -> bf16
// blocks 1024..1039 : W1^T -> bf16 (block 1024 also zeros BN stats)
// blocks 1040..1047 : xyz -> xyz4 (padded float4)
// blocks 1048..1111 : w[c][j][i] = exp(-|xyz_i - xyz_j|), one block per cloud
__global__ __launch_bounds__(256) void prep_kernel(
    const float* __restrict__ x, const float* __restrict__ W1,
    const float* __restrict__ xyz,
    unsigned short* __restrict__ xb, unsigned short* __restrict__ w1t,
    float* __restrict__ xyz4, float* __restrict__ w_ws,
    float* __restrict__ stat_ws)
{
    __shared__ float sx[512];
    const int bx = blockIdx.x, tid = threadIdx.x;
    if (bx < 1024) {
        const int base = bx * 1024 + tid * 4;
        floatx4 v = *(const floatx4*)(x + base);
        ushortx4 o = { f2bf(v[0]), f2bf(v[1]), f2bf(v[2]), f2bf(v[3]) };
        *(ushortx4*)(xb + base) = o;
    } else if (bx < 1040) {
        const int b2 = bx - 1024;             // 0..15
        const int n = b2 * 8 + (tid >> 5);    // 0..127
        const int k = (tid & 31) * 4;
#pragma unroll
        for (int e = 0; e < 4; ++e)
            w1t[n * 128 + k + e] = f2bf(W1[(k + e) * 128 + n]);
        if (b2 == 0) {
            floatx4 z = {0.f, 0.f, 0.f, 0.f};
            *(floatx4*)(stat_ws + tid * 4) = z;
        }
    } else if (bx < 1048) {
        const int node = (bx - 1040) * 1024 + tid * 4;
#pragma unroll
        for (int e = 0; e < 4; ++e) {
            const float* p = xyz + (node + e) * 3;
            floatx4 v = { p[0], p[1], p[2], 0.f };
            *(floatx4*)(xyz4 + (node + e) * 4) = v;
        }
    } else {
        const int cc = bx - 1048;             // cloud 0..63
        if (tid < 128) {
            const float* p = xyz + (cc * 128 + tid) * 3;
            sx[tid * 4 + 0] = p[0];
            sx[tid * 4 + 1] = p[1];
            sx[tid * 4 + 2] = p[2];
            sx[tid * 4 + 3] = 0.f;
        }
        __syncthreads();
        const int i = tid & 127, jh = tid >> 7;
        const float xi0 = sx[i * 4], xi1 = sx[i * 4 + 1], xi2 = sx[i * 4 + 2];
        float* wdst = w_ws + cc * 16384 + i;
        for (int jj = 0; jj < 64; ++jj) {
            const int j = jh * 64 + jj;
            float dx = xi0 - sx[j * 4];
            float dy = xi1 - sx[j * 4 + 1];
            float dz = xi2 - sx[j * 4 + 2];
            wdst[j * 128] = __expf(-sqrtf(dx * dx + dy * dy + dz * dz));
        }
    }
}

// ---------------- y = x @ W1 (bf16 MFMA, fp32 out). 512 blocks x 1 wave x 16 rows ----
__global__ __launch_bounds__(64) void gemm_y_kernel(
    const unsigned short* __restrict__ xb, const unsigned short* __restrict__ w1t,
    float* __restrict__ y)
{
    const int lane = threadIdx.x;
    const int ml = lane & 15, q = lane >> 4;
    const int rb = blockIdx.x * 16;

    short8 afrag[4];    // A[m=ml][k=32c+8q+j]
#pragma unroll
    for (int c = 0; c < 4; ++c)
        afrag[c] = *(const short8*)(xb + (rb + ml) * 128 + c * 32 + q * 8);

#pragma unroll
    for (int nt = 0; nt < 8; ++nt) {
        floatx4 acc = {0.f, 0.f, 0.f, 0.f};
        const int ncol = nt * 16 + ml;
#pragma unroll
        for (int c = 0; c < 4; ++c) {
            short8 b = *(const short8*)(w1t + ncol * 128 + c * 32 + q * 8);
            acc = __builtin_amdgcn_mfma_f32_16x16x32_bf16(afrag[c], b, acc, 0, 0, 0);
        }
#pragma unroll
        for (int r = 0; r < 4; ++r)
            y[(rb + q * 4 + r) * 128 + ncol] = acc[r];   // D: row=4q+r, col=ml (m89)
    }
}

// ---------------- main all-pairs kernel (LDS-free inner loop) ----------------
// grid = 1024: c = bx&63 (cloud), s = bx>>6 (split 0..15); 8 i's per block.
// block = 256: d = tid&127, h = tid>>7 (j-half). Per-j uniform operands (w, xyz)
// come from the scalar pipe (s_load); only yj is a vector load.
__global__ __launch_bounds__(256, 4) void cloud_main_kernel(
    const float* __restrict__ x, const float* __restrict__ W_xyz,
    const float* __restrict__ b1,
    const float* __restrict__ ln_gamma, const float* __restrict__ ln_beta,
    const float* __restrict__ xyz4, const float* __restrict__ w_ws,
    const float* __restrict__ y_ws, float* __restrict__ p2_ws,
    float* __restrict__ stat_ws, float* __restrict__ out)
{
    __shared__ float s_red[2048];   // h=1 partials: a1[8][128], a2[8][128]
    __shared__ float s_p1[1088];    // [8][136] merged p1 for LN reduce
    __shared__ float s_bn[256];     // BN partials per d
    __shared__ float s_mu[8];
    __shared__ float s_rs[8];

    const int bx = blockIdx.x;
    const int c = bx & 63, s = bx >> 6;
    const int tid = threadIdx.x;
    const int d = tid & 127, h = tid >> 7;
    const int node0 = c * 128;
    const int i0 = s * 8;

    const float w0 = W_xyz[d], w1c = W_xyz[128 + d], w2c = W_xyz[256 + d];
    const float b1d = b1[d];
    const floatx2 b1v = {b1d, b1d};
    const floatx2 zv2 = {0.f, 0.f};

    const float* __restrict__ wrow  = w_ws + c * 16384 + i0;   // + j*128 + e (uniform)
    const float* __restrict__ xzrow = xyz4 + node0 * 4;        // + j*4      (uniform)
    const float* __restrict__ yrow  = y_ws + node0 * 128 + d;  // + j*128    (vector)

    floatx2 yi[4], zi[4], a1[4], a2[4];
#pragma unroll
    for (int r = 0; r < 8; ++r) {
        const int ia = i0 + r;
        yi[r >> 1][r & 1] = yrow[ia * 128];
        const float* xi = xzrow + ia * 4;
        zi[r >> 1][r & 1] = xi[0] * w0 + xi[1] * w1c + xi[2] * w2c;
        a1[r >> 1][r & 1] = 0.f;
        a2[r >> 1][r & 1] = 0.f;
    }

    const int jbase = h * 64;
#pragma unroll 4
    for (int jj = 0; jj < 64; ++jj) {
        const int j = jbase + jj;
        const float yj = yrow[j * 128];                        // vector (L2-resident)
        floatx4 xj = *(const floatx4*)(xzrow + j * 4);         // scalar s_load_dwordx4
        const float zj = xj[0] * w0 + xj[1] * w1c + xj[2] * w2c;
        const float* wp = wrow + j * 128;                      // scalar s_load_dwordx8
        floatx2 w01 = { wp[0], wp[1] };
        floatx2 w23 = { wp[2], wp[3] };
        floatx2 w45 = { wp[4], wp[5] };
        floatx2 w67 = { wp[6], wp[7] };
        const floatx2 yj2 = {yj, yj}, zj2 = {zj, zj};
        a1[0] += __builtin_elementwise_max(w01 * (yi[0] - yj2) + b1v, zv2);
        a1[1] += __builtin_elementwise_max(w23 * (yi[1] - yj2) + b1v, zv2);
        a1[2] += __builtin_elementwise_max(w45 * (yi[2] - yj2) + b1v, zv2);
        a1[3] += __builtin_elementwise_max(w67 * (yi[3] - yj2) + b1v, zv2);
        a2[0] += __builtin_elementwise_max(zi[0] - zj2, zv2);
        a2[1] += __builtin_elementwise_max(zi[1] - zj2, zv2);
        a2[2] += __builtin_elementwise_max(zi[2] - zj2, zv2);
        a2[3] += __builtin_elementwise_max(zi[3] - zj2, zv2);
    }

    // h=1 publishes partials
    if (h == 1) {
#pragma unroll
        for (int r = 0; r < 8; ++r) {
            s_red[r * 128 + d]        = a1[r >> 1][r & 1];
            s_red[1024 + r * 128 + d] = a2[r >> 1][r & 1];
        }
    }
    __syncthreads();

    // h=0 merges, subtracts p1 self term (w_ii=1, diff=0 -> relu(b1d); p2 self = 0)
    if (h == 0) {
        const float selfc = fmaxf(b1d, 0.f);
        float bs = 0.f, bq = 0.f;
#pragma unroll
        for (int r = 0; r < 8; ++r) {
            float v1 = a1[r >> 1][r & 1] + s_red[r * 128 + d] - selfc;
            float v2 = a2[r >> 1][r & 1] + s_red[1024 + r * 128 + d];
            a1[r >> 1][r & 1] = v1;
            a2[r >> 1][r & 1] = v2;
            s_p1[r * 136 + d] = v1;
            bs += v2;
            bq += v2 * v2;
        }
        s_bn[d] = bs;
        s_bn[128 + d] = bq;
    }
    __syncthreads();

    // LN stats: 32 threads per i (8 i's x 32 = 256), 4 d's each, shuffle reduce
    {
        const int ii = tid >> 5, sub = tid & 31;
        floatx4 v = *(const floatx4*)(s_p1 + ii * 136 + sub * 4);
        float ps = v[0] + v[1] + v[2] + v[3];
        float pq = v[0] * v[0] + v[1] * v[1] + v[2] * v[2] + v[3] * v[3];
#pragma unroll
        for (int m = 1; m < 32; m <<= 1) {
            ps += __shfl_xor(ps, m, 64);
            pq += __shfl_xor(pq, m, 64);
        }
        if (sub == 0) {
            float mu = ps * (1.f / 128.f);
            float var = pq * (1.f / 128.f) - mu * mu;
            s_mu[ii] = mu;
            s_rs[ii] = rsqrtf(var + EPS);
        }
    }
    // BN partials -> 4 atomic banks
    if (tid < 128) {
        const int bank = (s & 3) * 256;
        atomicAdd(stat_ws + bank + d,       s_bn[d]);
        atomicAdd(stat_ws + bank + 128 + d, s_bn[128 + d]);
    }
    __syncthreads();

    // epilogue (h=0 holds merged): out = x + LN(p1)*lng + lnb ; store p2
    if (h == 0) {
        const float lng = ln_gamma[d], lnb = ln_beta[d];
#pragma unroll
        for (int r = 0; r < 8; ++r) {
            const int gi = node0 + i0 + r;
            float o = x[gi * 128 + d] + (a1[r >> 1][r & 1] - s_mu[r]) * s_rs[r] * lng + lnb;
            out[gi * 128 + d] = o;
            p2_ws[gi * 128 + d] = a2[r >> 1][r & 1];
        }
    }
}

// ---------------- finalize: out += BN(p2) ----------------
__global__ __launch_bounds__(256) void finalize_kernel(
    const float* __restrict__ p2_ws, const float* __restrict__ stat_ws,
    const float* __restrict__ bn_gamma, const float* __restrict__ bn_beta,
    float* __restrict__ out)
{
    __shared__ float sA[128], sB[128];
    const int tid = threadIdx.x;
    if (tid < 128) {
        float sm = 0.f, sq = 0.f;
#pragma unroll
        for (int b = 0; b < 4; ++b) {
            sm += stat_ws[b * 256 + tid];
            sq += stat_ws[b * 256 + 128 + tid];
        }
        float mu = sm * (1.f / 8192.f);
        float var = sq * (1.f / 8192.f) - mu * mu;
        float rs = rsqrtf(var + EPS);
        float A = rs * bn_gamma[tid];
        sA[tid] = A;
        sB[tid] = bn_beta[tid] - mu * A;
    }
    __syncthreads();
    const int base = (blockIdx.x * 256 + tid) * 4;
    const int d0 = base & 127;
    floatx4 p2 = *(const floatx4*)(p2_ws + base);
    floatx4 o  = *(const floatx4*)(out + base);
#pragma unroll
    for (int e = 0; e < 4; ++e)
        o[e] += p2[e] * sA[d0 + e] + sB[d0 + e];
    *(floatx4*)(out + base) = o;
}

extern "C" void kernel_launch(void* const* d_in, const int* in_sizes, int n_in,
                              void* d_out, int out_size, void* d_ws, size_t ws_size,
                              hipStream_t stream) {
    const float* x        = (const float*)d_in[0];
    const float* xyz      = (const float*)d_in[1];
    const float* W_xyz    = (const float*)d_in[2];
    const float* bn_gamma = (const float*)d_in[3];
    const float* bn_beta  = (const float*)d_in[4];
    const float* W1       = (const float*)d_in[5];
    const float* b1       = (const float*)d_in[6];
    const float* ln_gamma = (const float*)d_in[7];
    const float* ln_beta  = (const float*)d_in[8];
    float* out = (float*)d_out;

    float* y_ws    = (float*)d_ws;                       // [8192][128] fp32, 4 MB
    float* p2_ws   = y_ws + N_NODES * 128;               // [8192][128] fp32, 4 MB
    float* stat_ws = p2_ws + N_NODES * 128;              // 4 banks x (sum[128], sumsq[128])
    unsigned short* xb  = (unsigned short*)(stat_ws + 1024);  // [8192][128] bf16, 2 MB
    unsigned short* w1t = xb + N_NODES * 128;                 // [128][128] bf16 (transposed)
    float* xyz4 = (float*)(w1t + 128 * 128);             // [8192][4] fp32, 128 KB
    float* w_ws = xyz4 + N_NODES * 4;                    // [64][128 j][128 i] fp32, 4 MB

    prep_kernel<<<1112, 256, 0, stream>>>(x, W1, xyz, xb, w1t, xyz4, w_ws, stat_ws);
    gemm_y_kernel<<<512, 64, 0, stream>>>(xb, w1t, y_ws);
    cloud_main_kernel<<<1024, 256, 0, stream>>>(x, W_xyz, b1, ln_gamma, ln_beta,
                                                xyz4, w_ws, y_ws, p2_ws, stat_ws, out);
    finalize_kernel<<<1024, 256, 0, stream>>>(p2_ws, stat_ws, bn_gamma, bn_beta, out);
}

// Round 5
// 114.258 us; speedup vs baseline: 1.1258x; 1.1258x over previous
//
#include <hip/hip_runtime.h>
#include <stdint.h>

#define EPS 1e-5f
#define N_NODES 8192

typedef __attribute__((ext_vector_type(8))) short short8;
typedef __attribute__((ext_vector_type(4))) float floatx4;
typedef __attribute__((ext_vector_type(2))) float floatx2;
typedef __attribute__((ext_vector_type(4))) unsigned short ushortx4;

__device__ __forceinline__ unsigned short f2bf(float f) {
    uint32_t u = __float_as_uint(f);
    u += 0x7FFFu + ((u >> 16) & 1u);
    return (unsigned short)(u >> 16);
}

// ---------------- prep ----------------
// blocks    0..1023 : x -> bf16
// blocks 1024..1039 : W1^T -> bf16 (block 1024 also zeros BN stats)
// blocks 1040..1047 : xyz -> xyz4 (padded float4)
__global__ __launch_bounds__(256) void prep_kernel(
    const float* __restrict__ x, const float* __restrict__ W1,
    const float* __restrict__ xyz,
    unsigned short* __restrict__ xb, unsigned short* __restrict__ w1t,
    float* __restrict__ xyz4, float* __restrict__ stat_ws)
{
    const int bx = blockIdx.x, tid = threadIdx.x;
    if (bx < 1024) {
        const int base = bx * 1024 + tid * 4;
        floatx4 v = *(const floatx4*)(x + base);
        ushortx4 o = { f2bf(v[0]), f2bf(v[1]), f2bf(v[2]), f2bf(v[3]) };
        *(ushortx4*)(xb + base) = o;
    } else if (bx < 1040) {
        const int b2 = bx - 1024;             // 0..15
        const int n = b2 * 8 + (tid >> 5);    // 0..127
        const int k = (tid & 31) * 4;
#pragma unroll
        for (int e = 0; e < 4; ++e)
            w1t[n * 128 + k + e] = f2bf(W1[(k + e) * 128 + n]);
        if (b2 == 0) {
            floatx4 z = {0.f, 0.f, 0.f, 0.f};
            *(floatx4*)(stat_ws + tid * 4) = z;
        }
    } else {
        const int node = (bx - 1040) * 1024 + tid * 4;
#pragma unroll
        for (int e = 0; e < 4; ++e) {
            const float* p = xyz + (node + e) * 3;
            floatx4 v = { p[0], p[1], p[2], 0.f };
            *(floatx4*)(xyz4 + (node + e) * 4) = v;
        }
    }
}

// ---------------- yz: y = x@W1 (bf16 MFMA), z = xyz@W_xyz (3 FMA), interleaved ----
// 512 blocks x 1 wave x 16 rows. yz[node][d] = (y, z) pairs.
__global__ __launch_bounds__(64) void gemm_yz_kernel(
    const unsigned short* __restrict__ xb, const unsigned short* __restrict__ w1t,
    const float* __restrict__ xyz4, const float* __restrict__ W_xyz,
    float* __restrict__ yz)
{
    const int lane = threadIdx.x;
    const int ml = lane & 15, q = lane >> 4;
    const int rb = blockIdx.x * 16;

    short8 afrag[4];    // A[m=ml][k=32c+8q+j]
#pragma unroll
    for (int c = 0; c < 4; ++c)
        afrag[c] = *(const short8*)(xb + (rb + ml) * 128 + c * 32 + q * 8);

    floatx4 xn[4];      // xyz of this lane's 4 output rows (node = rb+q*4+r)
#pragma unroll
    for (int r = 0; r < 4; ++r)
        xn[r] = *(const floatx4*)(xyz4 + (rb + q * 4 + r) * 4);

#pragma unroll
    for (int nt = 0; nt < 8; ++nt) {
        const int ncol = nt * 16 + ml;
        const float wx0 = W_xyz[ncol], wx1 = W_xyz[128 + ncol], wx2 = W_xyz[256 + ncol];
        floatx4 acc = {0.f, 0.f, 0.f, 0.f};
#pragma unroll
        for (int c = 0; c < 4; ++c) {
            short8 b = *(const short8*)(w1t + ncol * 128 + c * 32 + q * 8);
            acc = __builtin_amdgcn_mfma_f32_16x16x32_bf16(afrag[c], b, acc, 0, 0, 0);
        }
#pragma unroll
        for (int r = 0; r < 4; ++r) {   // D: row=4q+r, col=ml (m89)
            const int node = rb + q * 4 + r;
            float zv = xn[r][0] * wx0 + xn[r][1] * wx1 + xn[r][2] * wx2;
            floatx2 st = { acc[r], zv };
            *(floatx2*)(yz + node * 256 + 2 * ncol) = st;
        }
    }
}

// ---------------- main all-pairs kernel ----------------
// grid = 1024: c = bx&63 (cloud), s = bx>>6 (split 0..15); 8 i's per block.
// block = 256: d = tid&127, h = tid>>7 (j-half). Per j: 1 coalesced dwordx2
// (y,z fused) + 2 broadcast ds_read_b128 (w pairs land pk-ready in VGPRs).
__global__ __launch_bounds__(256, 4) void cloud_main_kernel(
    const float* __restrict__ x, const float* __restrict__ b1,
    const float* __restrict__ ln_gamma, const float* __restrict__ ln_beta,
    const float* __restrict__ xyz4, const float* __restrict__ yz,
    float* __restrict__ p2_ws, float* __restrict__ stat_ws,
    float* __restrict__ out)
{
    __shared__ float s_xyz[512];    // [128][4]       (w-gen only)
    __shared__ float s_w[1024];     // [128 j][8 i]
    __shared__ float s_red[2048];   // h=1 partials: a1[8][128], a2[8][128]
    __shared__ float s_p1[1088];    // [8][136] merged p1 for LN reduce
    __shared__ float s_bn[256];     // BN partials per d
    __shared__ float s_mu[8];
    __shared__ float s_rs[8];

    const int bx = blockIdx.x;
    const int c = bx & 63, s = bx >> 6;
    const int tid = threadIdx.x;
    const int d = tid & 127, h = tid >> 7;
    const int node0 = c * 128;
    const int i0 = s * 8;

    // stage xyz (float4, aligned)
    if (tid < 128)
        *(floatx4*)(s_xyz + tid * 4) = *(const floatx4*)(xyz4 + (node0 + tid) * 4);
    __syncthreads();

    // w tile: w[j][ii] = exp(-|xyz_{i0+ii} - xyz_j|)
    for (int e = tid; e < 1024; e += 256) {
        const int j = e >> 3, ii = e & 7, ia = i0 + ii;
        float dx = s_xyz[ia * 4]     - s_xyz[j * 4];
        float dy = s_xyz[ia * 4 + 1] - s_xyz[j * 4 + 1];
        float dz = s_xyz[ia * 4 + 2] - s_xyz[j * 4 + 2];
        s_w[j * 8 + ii] = __expf(-sqrtf(dx * dx + dy * dy + dz * dz));
    }
    __syncthreads();

    const float b1d = b1[d];
    const floatx2 b1v = {b1d, b1d};
    const floatx2 zv2 = {0.f, 0.f};

    const float* __restrict__ yzrow = yz + node0 * 256 + 2 * d;

    floatx2 yi[4], zi[4], a1[4], a2[4];
#pragma unroll
    for (int r = 0; r < 8; ++r) {
        floatx2 v = *(const floatx2*)(yzrow + (i0 + r) * 256);
        yi[r >> 1][r & 1] = v[0];
        zi[r >> 1][r & 1] = v[1];
        a1[r >> 1][r & 1] = 0.f;
        a2[r >> 1][r & 1] = 0.f;
    }

    const float* __restrict__ yzp = yzrow + h * 64 * 256;
    const float* __restrict__ wp = s_w + h * 64 * 8;

#pragma unroll 4
    for (int jj = 0; jj < 64; ++jj) {
        floatx2 yzj = *(const floatx2*)(yzp + jj * 256);   // coalesced (y_j, z_j)
        floatx4 wa = *(const floatx4*)(wp + jj * 8);       // broadcast, pk-ready
        floatx4 wb = *(const floatx4*)(wp + jj * 8 + 4);   // broadcast, pk-ready
        const floatx2 yj2 = {yzj[0], yzj[0]}, zj2 = {yzj[1], yzj[1]};
        floatx2 w01 = {wa[0], wa[1]}, w23 = {wa[2], wa[3]};
        floatx2 w45 = {wb[0], wb[1]}, w67 = {wb[2], wb[3]};
        a1[0] += __builtin_elementwise_max(w01 * (yi[0] - yj2) + b1v, zv2);
        a1[1] += __builtin_elementwise_max(w23 * (yi[1] - yj2) + b1v, zv2);
        a1[2] += __builtin_elementwise_max(w45 * (yi[2] - yj2) + b1v, zv2);
        a1[3] += __builtin_elementwise_max(w67 * (yi[3] - yj2) + b1v, zv2);
        a2[0] += __builtin_elementwise_max(zi[0] - zj2, zv2);
        a2[1] += __builtin_elementwise_max(zi[1] - zj2, zv2);
        a2[2] += __builtin_elementwise_max(zi[2] - zj2, zv2);
        a2[3] += __builtin_elementwise_max(zi[3] - zj2, zv2);
    }

    // h=1 publishes partials
    if (h == 1) {
#pragma unroll
        for (int r = 0; r < 8; ++r) {
            s_red[r * 128 + d]        = a1[r >> 1][r & 1];
            s_red[1024 + r * 128 + d] = a2[r >> 1][r & 1];
        }
    }
    __syncthreads();

    // h=0 merges, subtracts p1 self term (w_ii=1, diff=0 -> relu(b1d); p2 self = 0)
    if (h == 0) {
        const float selfc = fmaxf(b1d, 0.f);
        float bs = 0.f, bq = 0.f;
#pragma unroll
        for (int r = 0; r < 8; ++r) {
            float v1 = a1[r >> 1][r & 1] + s_red[r * 128 + d] - selfc;
            float v2 = a2[r >> 1][r & 1] + s_red[1024 + r * 128 + d];
            a1[r >> 1][r & 1] = v1;
            a2[r >> 1][r & 1] = v2;
            s_p1[r * 136 + d] = v1;
            bs += v2;
            bq += v2 * v2;
        }
        s_bn[d] = bs;
        s_bn[128 + d] = bq;
    }
    __syncthreads();

    // LN stats: 32 threads per i (8 i's x 32 = 256), 4 d's each, shuffle reduce
    {
        const int ii = tid >> 5, sub = tid & 31;
        floatx4 v = *(const floatx4*)(s_p1 + ii * 136 + sub * 4);
        float ps = v[0] + v[1] + v[2] + v[3];
        float pq = v[0] * v[0] + v[1] * v[1] + v[2] * v[2] + v[3] * v[3];
#pragma unroll
        for (int m = 1; m < 32; m <<= 1) {
            ps += __shfl_xor(ps, m, 64);
            pq += __shfl_xor(pq, m, 64);
        }
        if (sub == 0) {
            float mu = ps * (1.f / 128.f);
            float var = pq * (1.f / 128.f) - mu * mu;
            s_mu[ii] = mu;
            s_rs[ii] = rsqrtf(var + EPS);
        }
    }
    // BN partials -> 4 atomic banks
    if (tid < 128) {
        const int bank = (s & 3) * 256;
        atomicAdd(stat_ws + bank + d,       s_bn[d]);
        atomicAdd(stat_ws + bank + 128 + d, s_bn[128 + d]);
    }
    __syncthreads();

    // epilogue (h=0 holds merged): out = x + LN(p1)*lng + lnb ; store p2
    if (h == 0) {
        const float lng = ln_gamma[d], lnb = ln_beta[d];
#pragma unroll
        for (int r = 0; r < 8; ++r) {
            const int gi = node0 + i0 + r;
            float o = x[gi * 128 + d] + (a1[r >> 1][r & 1] - s_mu[r]) * s_rs[r] * lng + lnb;
            out[gi * 128 + d] = o;
            p2_ws[gi * 128 + d] = a2[r >> 1][r & 1];
        }
    }
}

// ---------------- finalize: out += BN(p2) ----------------
__global__ __launch_bounds__(256) void finalize_kernel(
    const float* __restrict__ p2_ws, const float* __restrict__ stat_ws,
    const float* __restrict__ bn_gamma, const float* __restrict__ bn_beta,
    float* __restrict__ out)
{
    __shared__ float sA[128], sB[128];
    const int tid = threadIdx.x;
    if (tid < 128) {
        float sm = 0.f, sq = 0.f;
#pragma unroll
        for (int b = 0; b < 4; ++b) {
            sm += stat_ws[b * 256 + tid];
            sq += stat_ws[b * 256 + 128 + tid];
        }
        float mu = sm * (1.f / 8192.f);
        float var = sq * (1.f / 8192.f) - mu * mu;
        float rs = rsqrtf(var + EPS);
        float A = rs * bn_gamma[tid];
        sA[tid] = A;
        sB[tid] = bn_beta[tid] - mu * A;
    }
    __syncthreads();
    const int base = (blockIdx.x * 256 + tid) * 4;
    const int d0 = base & 127;
    floatx4 p2 = *(const floatx4*)(p2_ws + base);
    floatx4 o  = *(const floatx4*)(out + base);
#pragma unroll
    for (int e = 0; e < 4; ++e)
        o[e] += p2[e] * sA[d0 + e] + sB[d0 + e];
    *(floatx4*)(out + base) = o;
}

extern "C" void kernel_launch(void* const* d_in, const int* in_sizes, int n_in,
                              void* d_out, int out_size, void* d_ws, size_t ws_size,
                              hipStream_t stream) {
    const float* x        = (const float*)d_in[0];
    const float* xyz      = (const float*)d_in[1];
    const float* W_xyz    = (const float*)d_in[2];
    const float* bn_gamma = (const float*)d_in[3];
    const float* bn_beta  = (const float*)d_in[4];
    const float* W1       = (const float*)d_in[5];
    const float* b1       = (const float*)d_in[6];
    const float* ln_gamma = (const float*)d_in[7];
    const float* ln_beta  = (const float*)d_in[8];
    float* out = (float*)d_out;

    float* yz_ws   = (float*)d_ws;                       // [8192][128][2] fp32, 8 MB
    float* p2_ws   = yz_ws + N_NODES * 256;              // [8192][128] fp32, 4 MB
    float* stat_ws = p2_ws + N_NODES * 128;              // 4 banks x (sum[128], sumsq[128])
    unsigned short* xb  = (unsigned short*)(stat_ws + 1024);  // [8192][128] bf16, 2 MB
    unsigned short* w1t = xb + N_NODES * 128;                 // [128][128] bf16 (transposed)
    float* xyz4 = (float*)(w1t + 128 * 128);             // [8192][4] fp32, 128 KB

    prep_kernel<<<1048, 256, 0, stream>>>(x, W1, xyz, xb, w1t, xyz4, stat_ws);
    gemm_yz_kernel<<<512, 64, 0, stream>>>(xb, w1t, xyz4, W_xyz, yz_ws);
    cloud_main_kernel<<<1024, 256, 0, stream>>>(x, b1, ln_gamma, ln_beta,
                                                xyz4, yz_ws, p2_ws, stat_ws, out);
    finalize_kernel<<<1024, 256, 0, stream>>>(p2_ws, stat_ws, bn_gamma, bn_beta, out);
}